// Round 1
// baseline (292.755 us; speedup 1.0000x reference)
//
#include <hip/hip_runtime.h>
#include <hip/hip_fp16.h>

typedef _Float16 f16;
typedef _Float16 f16x4 __attribute__((ext_vector_type(4)));
typedef _Float16 f16x8 __attribute__((ext_vector_type(8)));
typedef float f32x4 __attribute__((ext_vector_type(4)));

#define B_ 256
#define N_ 2048
#define D_ 256
#define M_TOTAL (B_ * N_)      // 524288
#define BM 64
#define NTILES (M_TOTAL / BM)  // 8192
#define GRID_MAIN 512

// ---------------------------------------------------------------------------
// prep_w: W[0][d][k] (k<256, the feature half) -> fp16 hi/lo planes laid out in
// MFMA B-fragment order: plane[p][ctg][ks][lane][j], 65536 f16 per plane.
//   ctg = d>>4, lane = (d&15) | (((k>>3)&3)<<4), ks = k>>5, j = k&7
// ---------------------------------------------------------------------------
__global__ void prep_w(const float* __restrict__ W, f16* __restrict__ wbuf) {
    int idx = blockIdx.x * 256 + threadIdx.x;   // 65536 total
    int d = idx >> 8, k = idx & 255;
    float w = W[d * 512 + k];
    f16 hi = (f16)w;
    f16 lo = (f16)(w - (float)hi);
    int ctg  = d >> 4;
    int lane = (d & 15) | (((k >> 3) & 3) << 4);
    int ks   = k >> 5;
    int j    = k & 7;
    int off  = ((ctg * 8 + ks) * 64 + lane) * 8 + j;
    wbuf[off]         = hi;
    wbuf[65536 + off] = lo;
}

// ---------------------------------------------------------------------------
// prep_c: c[b][d] = sum_e W[0][d][256+e] * h[b][e]   (fp32 exact, tiny)
// ---------------------------------------------------------------------------
__global__ void prep_c(const float* __restrict__ W, const float* __restrict__ h,
                       float* __restrict__ c) {
    __shared__ float hs[256];
    int b = blockIdx.x, d = threadIdx.x;
    hs[d] = h[b * 256 + d];
    __syncthreads();
    const float4* w4 = (const float4*)(W + d * 512 + 256);
    const float4* h4 = (const float4*)hs;
    float acc = 0.f;
#pragma unroll 8
    for (int e = 0; e < 64; ++e) {
        float4 a = w4[e], bb = h4[e];
        acc += a.x * bb.x + a.y * bb.y + a.z * bb.z + a.w * bb.w;
    }
    c[b * 256 + d] = acc;
}

// ---------------------------------------------------------------------------
// main_gemm: per 64-row tile, inner[row][d] = feat*W1^T (+c) ; scores = v.tanh(inner)
// 8 waves x (32 cols each) covers D=256. W frags live in registers (hi+lo).
// Feature staged to LDS as fp16 hi/lo, XOR-swizzled, in 2 K-chunks of 128.
// 3-pass split precision: a_hi*W_hi + a_hi*W_lo + a_lo*W_hi.
// ---------------------------------------------------------------------------
__global__ __launch_bounds__(512, 2)
void main_gemm(const float* __restrict__ feat, const f16* __restrict__ wbuf,
               const float* __restrict__ cbuf, const float* __restrict__ vvec,
               float* __restrict__ scores) {
    __shared__ __align__(16) char lds[32768 + 2048];
    // Ahi: lds[0..16384)      [64 rows][128 k] f16, swizzled
    // Alo: lds[16384..32768)
    // buf: lds[32768..34816)  [64][8] f32

    const int tid = threadIdx.x;
    const int w = tid >> 6;       // wave 0..7
    const int l = tid & 63;
    const int wcol0 = w * 32;
    const int g = l >> 4;         // lane subgroup 0..3

    // ---- W fragments into registers: wf[plane][ct][ks], 128 VGPRs ----
    f16x8 wf[2][2][8];
    {
        const f16x8* wp = (const f16x8*)wbuf;  // 8192 f16x8 per plane
#pragma unroll
        for (int p = 0; p < 2; ++p)
#pragma unroll
            for (int ct = 0; ct < 2; ++ct) {
                int ctg = (wcol0 >> 4) + ct;
#pragma unroll
                for (int ks = 0; ks < 8; ++ks)
                    wf[p][ct][ks] = wp[p * 8192 + (ctg * 8 + ks) * 64 + l];
            }
    }
    const float vv0 = vvec[wcol0 + (l & 15)];
    const float vv1 = vvec[wcol0 + 16 + (l & 15)];

    const int srow_off = tid >> 5;       // 0..15
    const int skk = (tid & 31) * 4;      // k offset within chunk (elements)

    for (int mt = blockIdx.x; mt < NTILES; mt += gridDim.x) {
        const long m0 = (long)mt * BM;
        const int b = mt >> 5;           // 32 tiles per batch row-block
        f32x4 acc[4][2] = {};

#pragma unroll
        for (int kc = 0; kc < 2; ++kc) {
            __syncthreads();
            // ---- stage chunk: 64 rows x 128 k, fp32 -> fp16 hi/lo ----
#pragma unroll
            for (int i = 0; i < 4; ++i) {
                int row = i * 16 + srow_off;
                const float4 v4 = *(const float4*)(feat + (m0 + row) * 256 + kc * 128 + skk);
                f16 h0 = (f16)v4.x, h1 = (f16)v4.y, h2 = (f16)v4.z, h3 = (f16)v4.w;
                f16 l0 = (f16)(v4.x - (float)h0);
                f16 l1 = (f16)(v4.y - (float)h1);
                f16 l2 = (f16)(v4.z - (float)h2);
                f16 l3 = (f16)(v4.w - (float)h3);
                int byte = (row * 256 + skk * 2) ^ ((row & 7) << 4);
                f16x4 hv = {h0, h1, h2, h3};
                f16x4 lv = {l0, l1, l2, l3};
                *(f16x4*)(lds + byte)         = hv;
                *(f16x4*)(lds + 16384 + byte) = lv;
            }
            __syncthreads();
            // ---- compute: 4 k-steps of 32 ----
#pragma unroll
            for (int ks2 = 0; ks2 < 4; ++ks2) {
                const int ksg = kc * 4 + ks2;
#pragma unroll
                for (int rt = 0; rt < 4; ++rt) {
                    int row = rt * 16 + (l & 15);
                    int byte = (row * 256 + ks2 * 64 + g * 16) ^ ((row & 7) << 4);
                    f16x8 ah = *(const f16x8*)(lds + byte);
                    f16x8 al = *(const f16x8*)(lds + 16384 + byte);
                    acc[rt][0] = __builtin_amdgcn_mfma_f32_16x16x32_f16(ah, wf[0][0][ksg], acc[rt][0], 0, 0, 0);
                    acc[rt][1] = __builtin_amdgcn_mfma_f32_16x16x32_f16(ah, wf[0][1][ksg], acc[rt][1], 0, 0, 0);
                    acc[rt][0] = __builtin_amdgcn_mfma_f32_16x16x32_f16(ah, wf[1][0][ksg], acc[rt][0], 0, 0, 0);
                    acc[rt][1] = __builtin_amdgcn_mfma_f32_16x16x32_f16(ah, wf[1][1][ksg], acc[rt][1], 0, 0, 0);
                    acc[rt][0] = __builtin_amdgcn_mfma_f32_16x16x32_f16(al, wf[0][0][ksg], acc[rt][0], 0, 0, 0);
                    acc[rt][1] = __builtin_amdgcn_mfma_f32_16x16x32_f16(al, wf[0][1][ksg], acc[rt][1], 0, 0, 0);
                }
            }
        }

        // ---- epilogue: +c, tanh, *v, reduce over d ----
        const float c0 = cbuf[b * 256 + wcol0 + (l & 15)];
        const float c1 = cbuf[b * 256 + wcol0 + 16 + (l & 15)];
        float* buf = (float*)(lds + 32768);
#pragma unroll
        for (int rt = 0; rt < 4; ++rt) {
            float s[4];
#pragma unroll
            for (int r = 0; r < 4; ++r) {
                float x0 = acc[rt][0][r] + c0;
                float x1 = acc[rt][1][r] + c1;
                float e0 = __expf(2.f * x0);
                float e1 = __expf(2.f * x1);
                float t0 = 1.f - __fdividef(2.f, e0 + 1.f);
                float t1 = 1.f - __fdividef(2.f, e1 + 1.f);
                s[r] = vv0 * t0 + vv1 * t1;
            }
#pragma unroll
            for (int m = 1; m < 16; m <<= 1) {
                s[0] += __shfl_xor(s[0], m, 64);
                s[1] += __shfl_xor(s[1], m, 64);
                s[2] += __shfl_xor(s[2], m, 64);
                s[3] += __shfl_xor(s[3], m, 64);
            }
            if ((l & 15) == 0) {
                int r0 = rt * 16 + g * 4;
                buf[(r0 + 0) * 8 + w] = s[0];
                buf[(r0 + 1) * 8 + w] = s[1];
                buf[(r0 + 2) * 8 + w] = s[2];
                buf[(r0 + 3) * 8 + w] = s[3];
            }
        }
        __syncthreads();
        if (tid < 64) {
            float* buf = (float*)(lds + 32768);
            float s = 0.f;
#pragma unroll
            for (int ww = 0; ww < 8; ++ww) s += buf[tid * 8 + ww];
            scores[m0 + tid] = s;
        }
    }
}

// ---------------------------------------------------------------------------
// softmax over n (2048) per b; out[b*2048+n]
// ---------------------------------------------------------------------------
__global__ void softmax_k(const float* __restrict__ scores, float* __restrict__ out) {
    __shared__ float red[16];
    int b = blockIdx.x, tid = threadIdx.x;  // 256 threads
    const float4* s4 = (const float4*)(scores + b * 2048);
    float4 x0 = s4[tid], x1 = s4[tid + 256];
    float m = fmaxf(fmaxf(fmaxf(x0.x, x0.y), fmaxf(x0.z, x0.w)),
                    fmaxf(fmaxf(x1.x, x1.y), fmaxf(x1.z, x1.w)));
#pragma unroll
    for (int d = 1; d < 64; d <<= 1) m = fmaxf(m, __shfl_xor(m, d, 64));
    if ((tid & 63) == 0) red[tid >> 6] = m;
    __syncthreads();
    m = fmaxf(fmaxf(red[0], red[1]), fmaxf(red[2], red[3]));
    float e0 = __expf(x0.x - m), e1 = __expf(x0.y - m), e2 = __expf(x0.z - m), e3 = __expf(x0.w - m);
    float e4 = __expf(x1.x - m), e5 = __expf(x1.y - m), e6 = __expf(x1.z - m), e7 = __expf(x1.w - m);
    float sum = ((e0 + e1) + (e2 + e3)) + ((e4 + e5) + (e6 + e7));
#pragma unroll
    for (int d = 1; d < 64; d <<= 1) sum += __shfl_xor(sum, d, 64);
    if ((tid & 63) == 0) red[8 + (tid >> 6)] = sum;
    __syncthreads();
    sum = (red[8] + red[9]) + (red[10] + red[11]);
    float inv = __fdividef(1.f, sum);
    float4 o0 = {e0 * inv, e1 * inv, e2 * inv, e3 * inv};
    float4 o1 = {e4 * inv, e5 * inv, e6 * inv, e7 * inv};
    float4* o4 = (float4*)(out + b * 2048);
    o4[tid] = o0;
    o4[tid + 256] = o1;
}

// ---------------------------------------------------------------------------
extern "C" void kernel_launch(void* const* d_in, const int* in_sizes, int n_in,
                              void* d_out, int out_size, void* d_ws, size_t ws_size,
                              hipStream_t stream) {
    const float* feat = (const float*)d_in[0];   // [256,2048,256]
    const float* h    = (const float*)d_in[1];   // [256,256]
    const float* v    = (const float*)d_in[2];   // [256]
    const float* W    = (const float*)d_in[3];   // [256,512]
    float* out = (float*)d_out;                  // [256,1,2048]

    f16*   wbuf   = (f16*)d_ws;                          // 262144 B
    float* cbuf   = (float*)((char*)d_ws + 262144);      // 262144 B
    float* scores = (float*)((char*)d_ws + 524288);      // 2 MiB

    prep_w<<<256, 256, 0, stream>>>(W, wbuf);
    prep_c<<<256, 256, 0, stream>>>(W, h, cbuf);
    main_gemm<<<GRID_MAIN, 512, 0, stream>>>(feat, wbuf, cbuf, v, scores);
    softmax_k<<<256, 256, 0, stream>>>(scores, out);
}

// Round 2
// 226.572 us; speedup vs baseline: 1.2921x; 1.2921x over previous
//
#include <hip/hip_runtime.h>
#include <hip/hip_fp16.h>

typedef _Float16 f16;
typedef _Float16 f16x4 __attribute__((ext_vector_type(4)));
typedef _Float16 f16x8 __attribute__((ext_vector_type(8)));
typedef float f32x4 __attribute__((ext_vector_type(4)));

#define B_ 256
#define N_ 2048
#define D_ 256
#define M_TOTAL (B_ * N_)      // 524288
#define BM 64
#define NTILES (M_TOTAL / BM)  // 8192
#define GRID_MAIN 512
#define TPW (NTILES / GRID_MAIN)  // 16 tiles per workgroup

// ---------------------------------------------------------------------------
// prep_w: W[0][d][k] (k<256, feature half) -> fp16 hi/lo planes in MFMA
// B-fragment order: plane[p][ctg][ks][lane][j].
//   ctg = d>>4, lane = (d&15) | (((k>>3)&3)<<4), ks = k>>5, j = k&7
// ---------------------------------------------------------------------------
__global__ void prep_w(const float* __restrict__ W, f16* __restrict__ wbuf) {
    int idx = blockIdx.x * 256 + threadIdx.x;   // 65536 total
    int d = idx >> 8, k = idx & 255;
    float w = W[d * 512 + k];
    f16 hi = (f16)w;
    f16 lo = (f16)(w - (float)hi);
    int ctg  = d >> 4;
    int lane = (d & 15) | (((k >> 3) & 3) << 4);
    int ks   = k >> 5;
    int j    = k & 7;
    int off  = ((ctg * 8 + ks) * 64 + lane) * 8 + j;
    wbuf[off]         = hi;
    wbuf[65536 + off] = lo;
}

// ---------------------------------------------------------------------------
// prep_c: c[b][d] = sum_e W[0][d][256+e] * h[b][e]   (fp32 exact, tiny)
// ---------------------------------------------------------------------------
__global__ void prep_c(const float* __restrict__ W, const float* __restrict__ h,
                       float* __restrict__ c) {
    __shared__ float hs[256];
    int b = blockIdx.x, d = threadIdx.x;
    hs[d] = h[b * 256 + d];
    __syncthreads();
    const float4* w4 = (const float4*)(W + d * 512 + 256);
    const float4* h4 = (const float4*)hs;
    float acc = 0.f;
#pragma unroll 8
    for (int e = 0; e < 64; ++e) {
        float4 a = w4[e], bb = h4[e];
        acc += a.x * bb.x + a.y * bb.y + a.z * bb.z + a.w * bb.w;
    }
    c[b * 256 + d] = acc;
}

// ---------------------------------------------------------------------------
// staging helpers: 64 rows x 128 k chunk; 512 threads x 16 f32 each.
// iter i: row = i*32 + (tid>>4), k0 = (tid&15)*8. LDS layout fp16 hi only,
// XOR-swizzled: byte = (row*256 + k*2) ^ ((row&7)<<4).
// ---------------------------------------------------------------------------
__device__ __forceinline__ void stage_load(float4* st, const float* __restrict__ feat,
                                           long m0, int kc, int srow, int sk0) {
#pragma unroll
    for (int i = 0; i < 2; ++i) {
        const float* p = feat + (m0 + i * 32 + srow) * 256 + kc * 128 + sk0;
        st[i * 2 + 0] = *(const float4*)p;
        st[i * 2 + 1] = *(const float4*)(p + 4);
    }
}

__device__ __forceinline__ void stage_write(char* dst, const float4* st, int srow, int sk0) {
#pragma unroll
    for (int i = 0; i < 2; ++i) {
        int row = i * 32 + srow;
        f16x8 hv;
        hv[0] = (f16)st[i * 2 + 0].x; hv[1] = (f16)st[i * 2 + 0].y;
        hv[2] = (f16)st[i * 2 + 0].z; hv[3] = (f16)st[i * 2 + 0].w;
        hv[4] = (f16)st[i * 2 + 1].x; hv[5] = (f16)st[i * 2 + 1].y;
        hv[6] = (f16)st[i * 2 + 1].z; hv[7] = (f16)st[i * 2 + 1].w;
        int byte = (row * 256 + sk0 * 2) ^ ((row & 7) << 4);
        *(f16x8*)(dst + byte) = hv;
    }
}

// ---------------------------------------------------------------------------
// main_gemm: 2-pass split precision (f_hi*W_hi + f_hi*W_lo), double-buffered
// LDS, one barrier per chunk. 8 waves x 32 cols; W frags resident in VGPRs.
// ---------------------------------------------------------------------------
__global__ __launch_bounds__(512, 2)
void main_gemm(const float* __restrict__ feat, const f16* __restrict__ wbuf,
               const float* __restrict__ cb, const float* __restrict__ vvec,
               float* __restrict__ scores) {
    __shared__ __align__(16) char lds[32768 + 2304];
    // buf0: lds[0..16384), buf1: lds[16384..32768) — A hi-plane, swizzled
    // rbuf: lds[32768..)  [64][9] f32 (padded stride 9: conflict-free)

    const int tid = threadIdx.x;
    const int w = tid >> 6;       // wave 0..7
    const int l = tid & 63;
    const int wcol0 = w * 32;
    const int g = l >> 4;

    // ---- W fragments (hi+lo planes) into registers: 128 VGPRs ----
    f16x8 wf[2][2][8];
    {
        const f16x8* wp = (const f16x8*)wbuf;
#pragma unroll
        for (int p = 0; p < 2; ++p)
#pragma unroll
            for (int ct = 0; ct < 2; ++ct) {
                int ctg = (wcol0 >> 4) + ct;
#pragma unroll
                for (int ks = 0; ks < 8; ++ks)
                    wf[p][ct][ks] = wp[p * 8192 + (ctg * 8 + ks) * 64 + l];
            }
    }
    const float vv0 = vvec[wcol0 + (l & 15)];
    const float vv1 = vvec[wcol0 + 16 + (l & 15)];
    const int srow = tid >> 4;        // 0..31
    const int sk0 = (tid & 15) * 8;   // 0..120
    float* rbuf = (float*)(lds + 32768);

    // ---- prologue: stage chunk 0 of first tile into buf0 ----
    float4 st[4];
    stage_load(st, feat, (long)blockIdx.x * BM, 0, srow, sk0);
    stage_write(lds, st, srow, sk0);

    for (int t = 0; t < TPW; ++t) {
        const long mt = blockIdx.x + (long)t * GRID_MAIN;
        const long m0 = mt * BM;
        const int b = (int)(mt >> 5);
        f32x4 acc[4][2] = {};

#pragma unroll
        for (int kc = 0; kc < 2; ++kc) {
            __syncthreads();  // buf[kc] ready; buf[kc^1] free to overwrite
            const bool last = (t == TPW - 1) && (kc == 1);
            if (!last) {
                // issue next-chunk global loads AFTER the barrier (compiler
                // drains vmcnt(0) at __syncthreads); latency hides under MFMAs
                long nm0 = (kc == 0) ? m0 : (blockIdx.x + (long)(t + 1) * GRID_MAIN) * BM;
                stage_load(st, feat, nm0, kc ^ 1, srow, sk0);
            }
            char* abuf = lds + kc * 16384;
#pragma unroll
            for (int ks2 = 0; ks2 < 4; ++ks2) {
                const int ksg = kc * 4 + ks2;
#pragma unroll
                for (int rt = 0; rt < 4; ++rt) {
                    int row = rt * 16 + (l & 15);
                    int byte = (row * 256 + ks2 * 64 + g * 16) ^ ((row & 7) << 4);
                    f16x8 ah = *(const f16x8*)(abuf + byte);
                    acc[rt][0] = __builtin_amdgcn_mfma_f32_16x16x32_f16(ah, wf[0][0][ksg], acc[rt][0], 0, 0, 0);
                    acc[rt][1] = __builtin_amdgcn_mfma_f32_16x16x32_f16(ah, wf[0][1][ksg], acc[rt][1], 0, 0, 0);
                    acc[rt][0] = __builtin_amdgcn_mfma_f32_16x16x32_f16(ah, wf[1][0][ksg], acc[rt][0], 0, 0, 0);
                    acc[rt][1] = __builtin_amdgcn_mfma_f32_16x16x32_f16(ah, wf[1][1][ksg], acc[rt][1], 0, 0, 0);
                }
            }
            if (!last) stage_write(lds + (kc ^ 1) * 16384, st, srow, sk0);
        }

        // ---- epilogue: +c, tanh, *v, reduce over d ----
        const float c0 = cb[b * 256 + wcol0 + (l & 15)];
        const float c1 = cb[b * 256 + wcol0 + 16 + (l & 15)];
#pragma unroll
        for (int rt = 0; rt < 4; ++rt) {
            float s[4];
#pragma unroll
            for (int r = 0; r < 4; ++r) {
                float x0 = acc[rt][0][r] + c0;
                float x1 = acc[rt][1][r] + c1;
                float e0 = __expf(2.f * x0);
                float e1 = __expf(2.f * x1);
                float t0 = 1.f - __fdividef(2.f, e0 + 1.f);
                float t1 = 1.f - __fdividef(2.f, e1 + 1.f);
                s[r] = vv0 * t0 + vv1 * t1;
            }
#pragma unroll
            for (int m = 1; m < 16; m <<= 1) {
                s[0] += __shfl_xor(s[0], m, 64);
                s[1] += __shfl_xor(s[1], m, 64);
                s[2] += __shfl_xor(s[2], m, 64);
                s[3] += __shfl_xor(s[3], m, 64);
            }
            if ((l & 15) == 0) {
                int r0 = rt * 16 + g * 4;
                rbuf[(r0 + 0) * 9 + w] = s[0];
                rbuf[(r0 + 1) * 9 + w] = s[1];
                rbuf[(r0 + 2) * 9 + w] = s[2];
                rbuf[(r0 + 3) * 9 + w] = s[3];
            }
        }
        __syncthreads();
        if (tid < 64) {
            float s = 0.f;
#pragma unroll
            for (int ww = 0; ww < 8; ++ww) s += rbuf[tid * 9 + ww];
            scores[m0 + tid] = s;
        }
    }
}

// ---------------------------------------------------------------------------
// softmax over n (2048) per b; out[b*2048+n]
// ---------------------------------------------------------------------------
__global__ void softmax_k(const float* __restrict__ scores, float* __restrict__ out) {
    __shared__ float red[16];
    int b = blockIdx.x, tid = threadIdx.x;  // 256 threads
    const float4* s4 = (const float4*)(scores + b * 2048);
    float4 x0 = s4[tid], x1 = s4[tid + 256];
    float m = fmaxf(fmaxf(fmaxf(x0.x, x0.y), fmaxf(x0.z, x0.w)),
                    fmaxf(fmaxf(x1.x, x1.y), fmaxf(x1.z, x1.w)));
#pragma unroll
    for (int d = 1; d < 64; d <<= 1) m = fmaxf(m, __shfl_xor(m, d, 64));
    if ((tid & 63) == 0) red[tid >> 6] = m;
    __syncthreads();
    m = fmaxf(fmaxf(red[0], red[1]), fmaxf(red[2], red[3]));
    float e0 = __expf(x0.x - m), e1 = __expf(x0.y - m), e2 = __expf(x0.z - m), e3 = __expf(x0.w - m);
    float e4 = __expf(x1.x - m), e5 = __expf(x1.y - m), e6 = __expf(x1.z - m), e7 = __expf(x1.w - m);
    float sum = ((e0 + e1) + (e2 + e3)) + ((e4 + e5) + (e6 + e7));
#pragma unroll
    for (int d = 1; d < 64; d <<= 1) sum += __shfl_xor(sum, d, 64);
    if ((tid & 63) == 0) red[8 + (tid >> 6)] = sum;
    __syncthreads();
    sum = (red[8] + red[9]) + (red[10] + red[11]);
    float inv = __fdividef(1.f, sum);
    float4 o0 = {e0 * inv, e1 * inv, e2 * inv, e3 * inv};
    float4 o1 = {e4 * inv, e5 * inv, e6 * inv, e7 * inv};
    float4* o4 = (float4*)(out + b * 2048);
    o4[tid] = o0;
    o4[tid + 256] = o1;
}

// ---------------------------------------------------------------------------
extern "C" void kernel_launch(void* const* d_in, const int* in_sizes, int n_in,
                              void* d_out, int out_size, void* d_ws, size_t ws_size,
                              hipStream_t stream) {
    const float* feat = (const float*)d_in[0];   // [256,2048,256]
    const float* h    = (const float*)d_in[1];   // [256,256]
    const float* v    = (const float*)d_in[2];   // [256]
    const float* W    = (const float*)d_in[3];   // [256,512]
    float* out = (float*)d_out;                  // [256,1,2048]

    f16*   wbuf   = (f16*)d_ws;                          // 262144 B
    float* cbuf   = (float*)((char*)d_ws + 262144);      // 262144 B
    float* scores = (float*)((char*)d_ws + 524288);      // 2 MiB

    prep_w<<<256, 256, 0, stream>>>(W, wbuf);
    prep_c<<<256, 256, 0, stream>>>(W, h, cbuf);
    main_gemm<<<GRID_MAIN, 512, 0, stream>>>(feat, wbuf, cbuf, v, scores);
    softmax_k<<<256, 256, 0, stream>>>(scores, out);
}